// Round 3
// baseline (196.034 us; speedup 1.0000x reference)
//
#include <hip/hip_runtime.h>
#include <math.h>

typedef float v2f __attribute__((ext_vector_type(2)));

constexpr int BLOCK = 256;

__global__ __launch_bounds__(BLOCK) void polar3x3_kernel(
    const float* __restrict__ rot,
    const float* __restrict__ mat,
    float* __restrict__ outq,
    float* __restrict__ logdet,
    int N)
{
    const long long tid = (long long)blockIdx.x * BLOCK + threadIdx.x;
    const long long i0 = tid * 2;              // 2 matrices per thread
    if (i0 >= N) return;
    const bool full = (i0 + 1 < N);

    // ---- load 2 matrices = 18 consecutive floats (8B-aligned: i0*36 % 8 == 0)
    float X[18];
    if (full) {
        const v2f* rp2 = (const v2f*)(rot + i0 * 9);
        #pragma unroll
        for (int k = 0; k < 9; ++k) { v2f w = rp2[k]; X[2*k] = w.x; X[2*k+1] = w.y; }
    } else {
        const float* rp = rot + i0 * 9;
        #pragma unroll
        for (int k = 0; k < 9; ++k) X[k] = rp[k];
        #pragma unroll
        for (int k = 9; k < 18; ++k) X[k] = 0.f;
        X[9] = X[13] = X[17] = 1.f;            // identity: inert through the loop
    }

    // uniform 3x3 'mat' (scalarized by compiler)
    const float m0=mat[0], m1=mat[1], m2=mat[2], m3=mat[3], m4=mat[4],
                m5=mat[5], m6=mat[6], m7=mat[7], m8=mat[8];
    // det(M) in f64 (shared across both matrices)
    const double dM = (double)m0*((double)m4*m8-(double)m5*m7)
                    - (double)m1*((double)m3*m8-(double)m5*m6)
                    + (double)m2*((double)m3*m7-(double)m4*m6);

    // A = R*M (f32) and det(A) = det(R)*det(M) in f64 — the only f64 needed:
    // sign(det) picks the reflection branch; f32 cancellation can flip it.
    float detA[2];
    #pragma unroll
    for (int j = 0; j < 2; ++j) {
        float* p = &X[9*j];
        const float r0=p[0],r1=p[1],r2=p[2],r3=p[3],r4=p[4],r5=p[5],r6=p[6],r7=p[7],r8=p[8];
        const double dR = (double)r0*((double)r4*r8-(double)r5*r7)
                        - (double)r1*((double)r3*r8-(double)r5*r6)
                        + (double)r2*((double)r3*r7-(double)r4*r6);
        detA[j] = (float)(dR * dM);
        p[0]=fmaf(r0,m0,fmaf(r1,m3,r2*m6));
        p[1]=fmaf(r0,m1,fmaf(r1,m4,r2*m7));
        p[2]=fmaf(r0,m2,fmaf(r1,m5,r2*m8));
        p[3]=fmaf(r3,m0,fmaf(r4,m3,r5*m6));
        p[4]=fmaf(r3,m1,fmaf(r4,m4,r5*m7));
        p[5]=fmaf(r3,m2,fmaf(r4,m5,r5*m8));
        p[6]=fmaf(r6,m0,fmaf(r7,m3,r8*m6));
        p[7]=fmaf(r6,m1,fmaf(r7,m4,r8*m7));
        p[8]=fmaf(r6,m2,fmaf(r7,m5,r8*m8));
    }

    // ---- 5 Frobenius-scaled Newton steps: X <- 0.5*(g*X + g^-1 * X^-T).
    // s = 0.5*p*h, t = sign(det)*0.5*q*h with p=(nC2/nX2)^1/4, q=(nX2/nC2)^1/4,
    // h=adet^-1/2 — two independent rcp chains + shared rsq (short critical path).
    // kappa=1e9 -> ~1.01 after 5 scaled steps; final unscaled step squares that.
    #pragma unroll
    for (int it = 0; it < 5; ++it) {
        #pragma unroll
        for (int j = 0; j < 2; ++j) {
            float* p = &X[9*j];
            const float x0=p[0],x1=p[1],x2=p[2],x3=p[3],x4=p[4],x5=p[5],x6=p[6],x7=p[7],x8=p[8];
            const float c0=fmaf(x4,x8,-x5*x7), c1=fmaf(x5,x6,-x3*x8), c2=fmaf(x3,x7,-x4*x6);
            const float c3=fmaf(x2,x7,-x1*x8), c4=fmaf(x0,x8,-x2*x6), c5=fmaf(x1,x6,-x0*x7);
            const float c6=fmaf(x1,x5,-x2*x4), c7=fmaf(x2,x3,-x0*x5), c8=fmaf(x0,x4,-x1*x3);
            const float det = (it==0) ? detA[j] : fmaf(x0,c0,fmaf(x1,c1,x2*c2));
            const float adet = fmaxf(fabsf(det), 1e-30f);
            float nX2, nC2;
            { const float a=fmaf(x1,x1,x0*x0), b=fmaf(x3,x3,x2*x2),
                          e=fmaf(x5,x5,x4*x4), d=fmaf(x7,x7,x6*x6);
              nX2=(a+b)+(e+fmaf(x8,x8,d)); }
            { const float a=fmaf(c1,c1,c0*c0), b=fmaf(c3,c3,c2*c2),
                          e=fmaf(c5,c5,c4*c4), d=fmaf(c7,c7,c6*c6);
              nC2=(a+b)+(e+fmaf(c8,c8,d)); }
            const float h  = __builtin_amdgcn_rsqf(adet);
            const float pr = __builtin_amdgcn_sqrtf(__builtin_amdgcn_sqrtf(
                                 nC2*__builtin_amdgcn_rcpf(nX2)));
            const float qr = __builtin_amdgcn_sqrtf(__builtin_amdgcn_sqrtf(
                                 nX2*__builtin_amdgcn_rcpf(nC2)));
            const float s = 0.5f*pr*h;
            const float t = copysignf(0.5f*qr*h, det);
            p[0]=fmaf(s,x0,t*c0); p[1]=fmaf(s,x1,t*c1); p[2]=fmaf(s,x2,t*c2);
            p[3]=fmaf(s,x3,t*c3); p[4]=fmaf(s,x4,t*c4); p[5]=fmaf(s,x5,t*c5);
            p[6]=fmaf(s,x6,t*c6); p[7]=fmaf(s,x7,t*c7); p[8]=fmaf(s,x8,t*c8);
        }
    }

    // ---- final unscaled Newton step (kappa~1: scaling is a numerical no-op)
    #pragma unroll
    for (int j = 0; j < 2; ++j) {
        float* p = &X[9*j];
        const float x0=p[0],x1=p[1],x2=p[2],x3=p[3],x4=p[4],x5=p[5],x6=p[6],x7=p[7],x8=p[8];
        const float c0=fmaf(x4,x8,-x5*x7), c1=fmaf(x5,x6,-x3*x8), c2=fmaf(x3,x7,-x4*x6);
        const float c3=fmaf(x2,x7,-x1*x8), c4=fmaf(x0,x8,-x2*x6), c5=fmaf(x1,x6,-x0*x7);
        const float c6=fmaf(x1,x5,-x2*x4), c7=fmaf(x2,x3,-x0*x5), c8=fmaf(x0,x4,-x1*x3);
        const float det = fmaf(x0,c0,fmaf(x1,c1,x2*c2));
        const float t = 0.5f*__builtin_amdgcn_rcpf(det);
        p[0]=fmaf(0.5f,x0,t*c0); p[1]=fmaf(0.5f,x1,t*c1); p[2]=fmaf(0.5f,x2,t*c2);
        p[3]=fmaf(0.5f,x3,t*c3); p[4]=fmaf(0.5f,x4,t*c4); p[5]=fmaf(0.5f,x5,t*c5);
        p[6]=fmaf(0.5f,x6,t*c6); p[7]=fmaf(0.5f,x7,t*c7); p[8]=fmaf(0.5f,x8,t*c8);
    }

    // ---- stores: nontemporal (never re-read; preserve L3 for input lines)
    float* op = outq + i0 * 9;
    if (full) {
        v2f* op2 = (v2f*)op;
        #pragma unroll
        for (int k = 0; k < 9; ++k) {
            v2f w; w.x = X[2*k]; w.y = X[2*k+1];
            __builtin_nontemporal_store(w, op2 + k);
        }
        v2f z; z.x = 0.f; z.y = 0.f;
        __builtin_nontemporal_store(z, (v2f*)(logdet + i0));
    } else {
        #pragma unroll
        for (int k = 0; k < 9; ++k) op[k] = X[k];
        logdet[i0] = 0.f;
    }
}

extern "C" void kernel_launch(void* const* d_in, const int* in_sizes, int n_in,
                              void* d_out, int out_size, void* d_ws, size_t ws_size,
                              hipStream_t stream) {
    const float* rot = (const float*)d_in[0];
    const float* mat = (const float*)d_in[1];
    float* out = (float*)d_out;
    const int N = in_sizes[0] / 9;                 // 2,000,000
    float* logdet = out + (long long)N * 9;        // outputs concatenated flat
    const long long nthreads = (N + 1) / 2;
    const int nblocks = (int)((nthreads + BLOCK - 1) / BLOCK);
    polar3x3_kernel<<<nblocks, BLOCK, 0, stream>>>(rot, mat, out, logdet, N);
}

// Round 4
// 145.992 us; speedup vs baseline: 1.3428x; 1.3428x over previous
//
#include <hip/hip_runtime.h>
#include <math.h>

typedef float v2f __attribute__((ext_vector_type(2)));

constexpr int BLOCK = 256;

__global__ __launch_bounds__(BLOCK) void polar3x3_kernel(
    const float* __restrict__ rot,
    const float* __restrict__ mat,
    float* __restrict__ outq,
    float* __restrict__ logdet,
    int N)
{
    const long long tid = (long long)blockIdx.x * BLOCK + threadIdx.x;
    const long long i0 = tid * 2;              // 2 matrices per thread
    if (i0 >= N) return;
    const bool full = (i0 + 1 < N);

    // ---- load 2 matrices = 18 consecutive floats (8B-aligned: i0*36 % 8 == 0)
    float X[18];
    if (full) {
        const v2f* rp2 = (const v2f*)(rot + i0 * 9);
        #pragma unroll
        for (int k = 0; k < 9; ++k) { v2f w = rp2[k]; X[2*k] = w.x; X[2*k+1] = w.y; }
    } else {
        const float* rp = rot + i0 * 9;
        #pragma unroll
        for (int k = 0; k < 9; ++k) X[k] = rp[k];
        #pragma unroll
        for (int k = 9; k < 18; ++k) X[k] = 0.f;
        X[9] = X[13] = X[17] = 1.f;            // identity: inert through the loop
    }

    // uniform 3x3 'mat' (scalarized by compiler)
    const float m0=mat[0], m1=mat[1], m2=mat[2], m3=mat[3], m4=mat[4],
                m5=mat[5], m6=mat[6], m7=mat[7], m8=mat[8];
    // det(M) in f64 (shared across both matrices)
    const double dM = (double)m0*((double)m4*m8-(double)m5*m7)
                    - (double)m1*((double)m3*m8-(double)m5*m6)
                    + (double)m2*((double)m3*m7-(double)m4*m6);

    // A = R*M (f32) and det(A) = det(R)*det(M) in f64 — the only f64 needed:
    // sign(det) picks the reflection branch; f32 cancellation can flip it.
    float detA[2];
    #pragma unroll
    for (int j = 0; j < 2; ++j) {
        float* p = &X[9*j];
        const float r0=p[0],r1=p[1],r2=p[2],r3=p[3],r4=p[4],r5=p[5],r6=p[6],r7=p[7],r8=p[8];
        const double dR = (double)r0*((double)r4*r8-(double)r5*r7)
                        - (double)r1*((double)r3*r8-(double)r5*r6)
                        + (double)r2*((double)r3*r7-(double)r4*r6);
        detA[j] = (float)(dR * dM);
        p[0]=fmaf(r0,m0,fmaf(r1,m3,r2*m6));
        p[1]=fmaf(r0,m1,fmaf(r1,m4,r2*m7));
        p[2]=fmaf(r0,m2,fmaf(r1,m5,r2*m8));
        p[3]=fmaf(r3,m0,fmaf(r4,m3,r5*m6));
        p[4]=fmaf(r3,m1,fmaf(r4,m4,r5*m7));
        p[5]=fmaf(r3,m2,fmaf(r4,m5,r5*m8));
        p[6]=fmaf(r6,m0,fmaf(r7,m3,r8*m6));
        p[7]=fmaf(r6,m1,fmaf(r7,m4,r8*m7));
        p[8]=fmaf(r6,m2,fmaf(r7,m5,r8*m8));
    }

    // ---- 5 Frobenius-scaled Newton steps: X <- 0.5*(g*X + g^-1 * X^-T).
    // s = 0.5*p*h, t = sign(det)*0.5*q*h with p=(nC2/nX2)^1/4, q=(nX2/nC2)^1/4,
    // h=adet^-1/2 — two independent rcp chains + shared rsq (short critical path).
    // kappa=1e9 -> ~1.01 after 5 scaled steps; final unscaled step squares that.
    #pragma unroll
    for (int it = 0; it < 5; ++it) {
        #pragma unroll
        for (int j = 0; j < 2; ++j) {
            float* p = &X[9*j];
            const float x0=p[0],x1=p[1],x2=p[2],x3=p[3],x4=p[4],x5=p[5],x6=p[6],x7=p[7],x8=p[8];
            const float c0=fmaf(x4,x8,-x5*x7), c1=fmaf(x5,x6,-x3*x8), c2=fmaf(x3,x7,-x4*x6);
            const float c3=fmaf(x2,x7,-x1*x8), c4=fmaf(x0,x8,-x2*x6), c5=fmaf(x1,x6,-x0*x7);
            const float c6=fmaf(x1,x5,-x2*x4), c7=fmaf(x2,x3,-x0*x5), c8=fmaf(x0,x4,-x1*x3);
            const float det = (it==0) ? detA[j] : fmaf(x0,c0,fmaf(x1,c1,x2*c2));
            const float adet = fmaxf(fabsf(det), 1e-30f);
            float nX2, nC2;
            { const float a=fmaf(x1,x1,x0*x0), b=fmaf(x3,x3,x2*x2),
                          e=fmaf(x5,x5,x4*x4), d=fmaf(x7,x7,x6*x6);
              nX2=(a+b)+(e+fmaf(x8,x8,d)); }
            { const float a=fmaf(c1,c1,c0*c0), b=fmaf(c3,c3,c2*c2),
                          e=fmaf(c5,c5,c4*c4), d=fmaf(c7,c7,c6*c6);
              nC2=(a+b)+(e+fmaf(c8,c8,d)); }
            const float h  = __builtin_amdgcn_rsqf(adet);
            const float pr = __builtin_amdgcn_sqrtf(__builtin_amdgcn_sqrtf(
                                 nC2*__builtin_amdgcn_rcpf(nX2)));
            const float qr = __builtin_amdgcn_sqrtf(__builtin_amdgcn_sqrtf(
                                 nX2*__builtin_amdgcn_rcpf(nC2)));
            const float s = 0.5f*pr*h;
            const float t = copysignf(0.5f*qr*h, det);
            p[0]=fmaf(s,x0,t*c0); p[1]=fmaf(s,x1,t*c1); p[2]=fmaf(s,x2,t*c2);
            p[3]=fmaf(s,x3,t*c3); p[4]=fmaf(s,x4,t*c4); p[5]=fmaf(s,x5,t*c5);
            p[6]=fmaf(s,x6,t*c6); p[7]=fmaf(s,x7,t*c7); p[8]=fmaf(s,x8,t*c8);
        }
    }

    // ---- final unscaled Newton step (kappa~1: scaling is a numerical no-op)
    #pragma unroll
    for (int j = 0; j < 2; ++j) {
        float* p = &X[9*j];
        const float x0=p[0],x1=p[1],x2=p[2],x3=p[3],x4=p[4],x5=p[5],x6=p[6],x7=p[7],x8=p[8];
        const float c0=fmaf(x4,x8,-x5*x7), c1=fmaf(x5,x6,-x3*x8), c2=fmaf(x3,x7,-x4*x6);
        const float c3=fmaf(x2,x7,-x1*x8), c4=fmaf(x0,x8,-x2*x6), c5=fmaf(x1,x6,-x0*x7);
        const float c6=fmaf(x1,x5,-x2*x4), c7=fmaf(x2,x3,-x0*x5), c8=fmaf(x0,x4,-x1*x3);
        const float det = fmaf(x0,c0,fmaf(x1,c1,x2*c2));
        const float t = 0.5f*__builtin_amdgcn_rcpf(det);
        p[0]=fmaf(0.5f,x0,t*c0); p[1]=fmaf(0.5f,x1,t*c1); p[2]=fmaf(0.5f,x2,t*c2);
        p[3]=fmaf(0.5f,x3,t*c3); p[4]=fmaf(0.5f,x4,t*c4); p[5]=fmaf(0.5f,x5,t*c5);
        p[6]=fmaf(0.5f,x6,t*c6); p[7]=fmaf(0.5f,x7,t*c7); p[8]=fmaf(0.5f,x8,t*c8);
    }

    // ---- stores: PLAIN (L2 write-allocate merges the wave's partial-line
    // stores into full 64B lines — round-2 counters showed exactly-ideal
    // 78 MB WRITE_SIZE. Nontemporal defeated that merge: 206 MB, 2.6x. )
    float* op = outq + i0 * 9;
    if (full) {
        v2f* op2 = (v2f*)op;
        #pragma unroll
        for (int k = 0; k < 9; ++k) {
            v2f w; w.x = X[2*k]; w.y = X[2*k+1];
            op2[k] = w;
        }
        v2f z; z.x = 0.f; z.y = 0.f;
        *(v2f*)(logdet + i0) = z;
    } else {
        #pragma unroll
        for (int k = 0; k < 9; ++k) op[k] = X[k];
        logdet[i0] = 0.f;
    }
}

extern "C" void kernel_launch(void* const* d_in, const int* in_sizes, int n_in,
                              void* d_out, int out_size, void* d_ws, size_t ws_size,
                              hipStream_t stream) {
    const float* rot = (const float*)d_in[0];
    const float* mat = (const float*)d_in[1];
    float* out = (float*)d_out;
    const int N = in_sizes[0] / 9;                 // 2,000,000
    float* logdet = out + (long long)N * 9;        // outputs concatenated flat
    const long long nthreads = (N + 1) / 2;
    const int nblocks = (int)((nthreads + BLOCK - 1) / BLOCK);
    polar3x3_kernel<<<nblocks, BLOCK, 0, stream>>>(rot, mat, out, logdet, N);
}

// Round 5
// 138.840 us; speedup vs baseline: 1.4119x; 1.0515x over previous
//
#include <hip/hip_runtime.h>
#include <math.h>

constexpr int BLOCK = 256;

__global__ __launch_bounds__(BLOCK) void polar3x3_kernel(
    const float* __restrict__ rot,
    const float* __restrict__ mat,
    float* __restrict__ outq,
    float* __restrict__ logdet,
    int N)
{
    // LDS staging: the ONLY access pattern where each cache line is touched
    // once per wave (r1 measured VALUBusy 86.6%, 0 bank conflicts with this
    // skeleton). Strided per-lane global access (r2/r4) touches 36-72 lines
    // per wave-instruction and stalls on load latency (VALUBusy 41-49%).
    __shared__ float lds[BLOCK * 9];
    const int tid = threadIdx.x;
    const long long base = (long long)blockIdx.x * BLOCK;
    const int rem = (int)(N - base);
    const int nmat = rem < BLOCK ? rem : BLOCK;
    const int nflt = nmat * 9;
    const int nv4 = nflt >> 2;

    // ---- stage in: coalesced float4 (block base 16B-aligned: 256*36=9216)
    const float* gsrc = rot + base * 9;
    {
        const float4* g4 = (const float4*)gsrc;
        float4* l4 = (float4*)lds;
        for (int i = tid; i < nv4; i += BLOCK) l4[i] = g4[i];
        for (int i = (nv4 << 2) + tid; i < nflt; i += BLOCK) lds[i] = gsrc[i];
    }

    // uniform 3x3 'mat' (scalarized); det(M) in f64
    const float m0=mat[0], m1=mat[1], m2=mat[2], m3=mat[3], m4=mat[4],
                m5=mat[5], m6=mat[6], m7=mat[7], m8=mat[8];
    const double dM = (double)m0*((double)m4*m8-(double)m5*m7)
                    - (double)m1*((double)m3*m8-(double)m5*m6)
                    + (double)m2*((double)m3*m7-(double)m4*m6);
    __syncthreads();

    const bool active = tid < nmat;
    // identity default keeps inactive lanes numerically inert
    float x0=1.f,x1=0.f,x2=0.f,x3=0.f,x4=1.f,x5=0.f,x6=0.f,x7=0.f,x8=1.f;
    float detA = 1.f;

    if (active) {
        // stride-9 b32 reads: bank (9i+k)%32, 2-way alias = free (m136; r1: 0 conflicts)
        const float* r = &lds[tid * 9];
        const float r0=r[0],r1=r[1],r2=r[2],r3=r[3],r4=r[4],r5=r[5],r6=r[6],r7=r[7],r8=r[8];
        // det(A)=det(R)*det(M) in f64 — the ONLY f64 needed: sign(det) picks
        // the reflection branch; f32 cancellation can flip it near det~1e-7.
        const double dR = (double)r0*((double)r4*r8-(double)r5*r7)
                        - (double)r1*((double)r3*r8-(double)r5*r6)
                        + (double)r2*((double)r3*r7-(double)r4*r6);
        detA = (float)(dR * dM);
        x0=fmaf(r0,m0,fmaf(r1,m3,r2*m6));
        x1=fmaf(r0,m1,fmaf(r1,m4,r2*m7));
        x2=fmaf(r0,m2,fmaf(r1,m5,r2*m8));
        x3=fmaf(r3,m0,fmaf(r4,m3,r5*m6));
        x4=fmaf(r3,m1,fmaf(r4,m4,r5*m7));
        x5=fmaf(r3,m2,fmaf(r4,m5,r5*m8));
        x6=fmaf(r6,m0,fmaf(r7,m3,r8*m6));
        x7=fmaf(r6,m1,fmaf(r7,m4,r8*m7));
        x8=fmaf(r6,m2,fmaf(r7,m5,r8*m8));
    }

    // ---- 5 Frobenius-scaled Newton steps: X <- 0.5*(g*X + g^-1 * X^-T).
    // s=0.5*p*h, t=sign(det)*0.5*q*h with p=(nC2/nX2)^1/4, q=(nX2/nC2)^1/4,
    // h=adet^-1/2 — two independent rcp chains + shared rsq. Scaling factors
    // need only ~1% accuracy (polar-invariant, self-healing) -> HW approx ops.
    #pragma unroll
    for (int it = 0; it < 5; ++it) {
        const float c0=fmaf(x4,x8,-x5*x7), c1=fmaf(x5,x6,-x3*x8), c2=fmaf(x3,x7,-x4*x6);
        const float c3=fmaf(x2,x7,-x1*x8), c4=fmaf(x0,x8,-x2*x6), c5=fmaf(x1,x6,-x0*x7);
        const float c6=fmaf(x1,x5,-x2*x4), c7=fmaf(x2,x3,-x0*x5), c8=fmaf(x0,x4,-x1*x3);
        const float det = (it==0) ? detA : fmaf(x0,c0,fmaf(x1,c1,x2*c2));
        const float adet = fmaxf(fabsf(det), 1e-30f);
        float nX2, nC2;
        { const float a=fmaf(x1,x1,x0*x0), b=fmaf(x3,x3,x2*x2),
                      e=fmaf(x5,x5,x4*x4), d=fmaf(x7,x7,x6*x6);
          nX2=(a+b)+(e+fmaf(x8,x8,d)); }
        { const float a=fmaf(c1,c1,c0*c0), b=fmaf(c3,c3,c2*c2),
                      e=fmaf(c5,c5,c4*c4), d=fmaf(c7,c7,c6*c6);
          nC2=(a+b)+(e+fmaf(c8,c8,d)); }
        const float h  = __builtin_amdgcn_rsqf(adet);
        const float pr = __builtin_amdgcn_sqrtf(__builtin_amdgcn_sqrtf(
                             nC2*__builtin_amdgcn_rcpf(nX2)));
        const float qr = __builtin_amdgcn_sqrtf(__builtin_amdgcn_sqrtf(
                             nX2*__builtin_amdgcn_rcpf(nC2)));
        const float s = 0.5f*pr*h;
        const float t = copysignf(0.5f*qr*h, det);
        x0=fmaf(s,x0,t*c0); x1=fmaf(s,x1,t*c1); x2=fmaf(s,x2,t*c2);
        x3=fmaf(s,x3,t*c3); x4=fmaf(s,x4,t*c4); x5=fmaf(s,x5,t*c5);
        x6=fmaf(s,x6,t*c6); x7=fmaf(s,x7,t*c7); x8=fmaf(s,x8,t*c8);
    }
    // ---- final unscaled Newton step (kappa~1: scaling is a numerical no-op)
    {
        const float c0=fmaf(x4,x8,-x5*x7), c1=fmaf(x5,x6,-x3*x8), c2=fmaf(x3,x7,-x4*x6);
        const float c3=fmaf(x2,x7,-x1*x8), c4=fmaf(x0,x8,-x2*x6), c5=fmaf(x1,x6,-x0*x7);
        const float c6=fmaf(x1,x5,-x2*x4), c7=fmaf(x2,x3,-x0*x5), c8=fmaf(x0,x4,-x1*x3);
        const float det = fmaf(x0,c0,fmaf(x1,c1,x2*c2));
        const float t = 0.5f*__builtin_amdgcn_rcpf(det);
        x0=fmaf(0.5f,x0,t*c0); x1=fmaf(0.5f,x1,t*c1); x2=fmaf(0.5f,x2,t*c2);
        x3=fmaf(0.5f,x3,t*c3); x4=fmaf(0.5f,x4,t*c4); x5=fmaf(0.5f,x5,t*c5);
        x6=fmaf(0.5f,x6,t*c6); x7=fmaf(0.5f,x7,t*c7); x8=fmaf(0.5f,x8,t*c8);
    }

    // own-slot write needs no barrier (only this thread read slot tid)
    if (active) {
        float* w = &lds[tid * 9];
        w[0]=x0; w[1]=x1; w[2]=x2; w[3]=x3; w[4]=x4;
        w[5]=x5; w[6]=x6; w[7]=x7; w[8]=x8;
    }
    __syncthreads();

    // ---- stage out: coalesced float4 plain stores (L2 write-allocate merges
    // to full lines — r2 measured exactly-ideal 78 MB WRITE_SIZE)
    float* gdst = outq + base * 9;
    {
        float4* g4 = (float4*)gdst;
        const float4* l4 = (const float4*)lds;
        for (int i = tid; i < nv4; i += BLOCK) g4[i] = l4[i];
        for (int i = (nv4 << 2) + tid; i < nflt; i += BLOCK) gdst[i] = lds[i];
    }

    // logdet: coalesced dword store (d_out re-poisoned 0xAA each launch)
    if (base + tid < N) logdet[base + tid] = 0.0f;
}

extern "C" void kernel_launch(void* const* d_in, const int* in_sizes, int n_in,
                              void* d_out, int out_size, void* d_ws, size_t ws_size,
                              hipStream_t stream) {
    const float* rot = (const float*)d_in[0];
    const float* mat = (const float*)d_in[1];
    float* out = (float*)d_out;
    const int N = in_sizes[0] / 9;                 // 2,000,000
    float* logdet = out + (long long)N * 9;        // outputs concatenated flat
    const int nblocks = (N + BLOCK - 1) / BLOCK;
    polar3x3_kernel<<<nblocks, BLOCK, 0, stream>>>(rot, mat, out, logdet, N);
}